// Round 7
// baseline (12583.579 us; speedup 1.0000x reference)
//
#include <hip/hip_runtime.h>
#include <hip/hip_bf16.h>
#include <math.h>

typedef long long i64;

// ==================== block reduce helpers (256 threads, fp32) ====================
__device__ __forceinline__ float2 blockSum2_256(float a, float b, float* red) {
#pragma unroll
  for (int off = 32; off; off >>= 1) {
    a += __shfl_xor(a, off, 64);
    b += __shfl_xor(b, off, 64);
  }
  __syncthreads();
  if ((threadIdx.x & 63) == 0) {
    int w = threadIdx.x >> 6;
    red[w * 2 + 0] = a;
    red[w * 2 + 1] = b;
  }
  __syncthreads();
  return make_float2(red[0] + red[2] + red[4] + red[6],
                     red[1] + red[3] + red[5] + red[7]);
}

__device__ __forceinline__ float lnVal(float v, float g, float b, float* red) {
  float2 s = blockSum2_256(v, v * v, red);
  float mean = s.x * (1.0f / 256.0f);
  float var = s.y * (1.0f / 256.0f) - mean * mean;
  var = fmaxf(var, 0.0f);
  return (v - mean) * rsqrtf(var + 1e-5f) * g + b;
}

// ==================== 1024-thread double block reduce (scan) ====================
__device__ __forceinline__ double2 blockSum2d_1024(double a, double b, double* red) {
#pragma unroll
  for (int off = 32; off; off >>= 1) {
    a += __shfl_xor(a, off, 64);
    b += __shfl_xor(b, off, 64);
  }
  __syncthreads();  // protect red[] from previous readers
  if ((threadIdx.x & 63) == 0) {
    int w = threadIdx.x >> 6;
    red[w * 2 + 0] = a;
    red[w * 2 + 1] = b;
  }
  __syncthreads();
  double sa = 0.0, sb = 0.0;
#pragma unroll
  for (int i = 0; i < 16; ++i) { sa += red[i * 2]; sb += red[i * 2 + 1]; }
  double2 r; r.x = sa; r.y = sb; return r;
}

// ==================== generic GEMM: C = act(A@W^T + bias) + add ====================
template <typename ACCT>
__global__ __launch_bounds__(256)
void gemm_nt_t(const float* __restrict__ A, int lda,
               const float* __restrict__ W, int ldw,
               const float* __restrict__ bias,
               const float* add,
               float* C, int ldc,
               int M, int N, int K, int relu)
{
  __shared__ float As[16][68];
  __shared__ float Ws[16][68];
  const int tid = threadIdx.x;
  const int tx = tid & 15, ty = tid >> 4;
  const int m0 = blockIdx.y * 64, n0 = blockIdx.x * 64;
  const int lrow = tid >> 2, lk = (tid & 3) << 2;
  ACCT acc[4][4] = {};
  for (int k0 = 0; k0 < K; k0 += 16) {
    float4 av = make_float4(0.f, 0.f, 0.f, 0.f);
    if (m0 + lrow < M) av = *(const float4*)(A + (i64)(m0 + lrow) * lda + k0 + lk);
    float4 wv = *(const float4*)(W + (i64)(n0 + lrow) * ldw + k0 + lk);
    As[lk + 0][lrow] = av.x; As[lk + 1][lrow] = av.y;
    As[lk + 2][lrow] = av.z; As[lk + 3][lrow] = av.w;
    Ws[lk + 0][lrow] = wv.x; Ws[lk + 1][lrow] = wv.y;
    Ws[lk + 2][lrow] = wv.z; Ws[lk + 3][lrow] = wv.w;
    __syncthreads();
#pragma unroll
    for (int kk = 0; kk < 16; ++kk) {
      ACCT a0 = (ACCT)As[kk][ty * 4 + 0], a1 = (ACCT)As[kk][ty * 4 + 1];
      ACCT a2 = (ACCT)As[kk][ty * 4 + 2], a3 = (ACCT)As[kk][ty * 4 + 3];
      ACCT b0 = (ACCT)Ws[kk][tx * 4 + 0], b1 = (ACCT)Ws[kk][tx * 4 + 1];
      ACCT b2 = (ACCT)Ws[kk][tx * 4 + 2], b3 = (ACCT)Ws[kk][tx * 4 + 3];
      acc[0][0] += a0 * b0; acc[0][1] += a0 * b1; acc[0][2] += a0 * b2; acc[0][3] += a0 * b3;
      acc[1][0] += a1 * b0; acc[1][1] += a1 * b1; acc[1][2] += a1 * b2; acc[1][3] += a1 * b3;
      acc[2][0] += a2 * b0; acc[2][1] += a2 * b1; acc[2][2] += a2 * b2; acc[2][3] += a2 * b3;
      acc[3][0] += a3 * b0; acc[3][1] += a3 * b1; acc[3][2] += a3 * b2; acc[3][3] += a3 * b3;
    }
    __syncthreads();
  }
#pragma unroll
  for (int i = 0; i < 4; ++i) {
    int m = m0 + ty * 4 + i;
    if (m >= M) continue;
#pragma unroll
    for (int j = 0; j < 4; ++j) {
      int n = n0 + tx * 4 + j;
      ACCT v = acc[i][j];
      if (bias) v += (ACCT)bias[n];
      if (relu) v = v > (ACCT)0 ? v : (ACCT)0;
      if (add) v += (ACCT)add[(i64)m * ldc + n];
      C[(i64)m * ldc + n] = (float)v;
    }
  }
}

// ==================== weight packing for the scan ====================
// W4h  [64][256][4]: W4h[(k>>2)*1024 + j*4 + (k&3)] = ode_W[j*1024 + k]   (k<256, j<256)
// W4hh [64][768][4]: W4hh[(k>>2)*3072 + j3*4 + (k&3)] = gru_Whh[j3*256 + k]
__global__ __launch_bounds__(256)
void pack_weights(const float* __restrict__ odeW, const float* __restrict__ Whh,
                  float* __restrict__ W4h, float* __restrict__ W4hh)
{
  int idx = blockIdx.x * 256 + threadIdx.x;
  if (idx < 65536) {
    int j = idx >> 8, k = idx & 255;
    W4h[((k >> 2) << 10) + (j << 2) + (k & 3)] = odeW[j * 1024 + k];
  } else {
    int t = idx - 65536;
    int j3 = t >> 8, k = t & 255;
    W4hh[(k >> 2) * 3072 + (j3 << 2) + (k & 3)] = Whh[j3 * 256 + k];
  }
}

// ==================== dx = (x_t - x_{t-1}) / dt  (double math, fp32 store) ====================
__global__ __launch_bounds__(256)
void dx_kernel(const float* __restrict__ x, const float* __restrict__ ts,
               float* __restrict__ dx)
{
  i64 row = blockIdx.x;  // b*512 + t
  int c = threadIdx.x;
  int t = (int)(row & 511);
  float v = 0.0f;
  if (t > 0) {
    double dt = (double)ts[row] - (double)ts[row - 1];
    v = (float)(((double)x[row * 256 + c] - (double)x[(row - 1) * 256 + c]) / dt);
  }
  dx[row * 256 + c] = v;
}

// ==================== silu elementwise ====================
__global__ __launch_bounds__(256)
void silu_kernel(const float* __restrict__ in, float* __restrict__ out)
{
  i64 i = (i64)blockIdx.x * 256 + threadIdx.x;
  float v = in[i];
  out[i] = v / (1.0f + __expf(-v));
}

// ==================== sentinel fill (ws too small diagnostic) ====================
__global__ __launch_bounds__(256)
void fill_kernel(float* __restrict__ out, float v)
{
  i64 i = (i64)blockIdx.x * 256 + threadIdx.x;
  out[i] = v;
}

__device__ __forceinline__ unsigned short f2bf(float x) {
  __hip_bfloat16 b = __float2bfloat16(x);   // RNE
  return *reinterpret_cast<unsigned short*>(&b);
}

// bf16 dot over 64-k slice: weights from LDS (uint2 = 4 bf16), k-vector broadcast
__device__ __forceinline__ float dot64bf(const uint2* __restrict__ wbrow, int j,
                                         const float* __restrict__ v)
{
  float a0 = 0.f, a1 = 0.f, a2 = 0.f, a3 = 0.f;
#pragma unroll
  for (int m = 0; m < 16; ++m) {
    uint2 w = wbrow[(m << 8) + j];
    float4 kv = *(const float4*)(v + (m << 2));
    a0 = fmaf(__uint_as_float(w.x << 16), kv.x, a0);
    a1 = fmaf(__uint_as_float(w.x & 0xffff0000u), kv.y, a1);
    a2 = fmaf(__uint_as_float(w.y << 16), kv.z, a2);
    a3 = fmaf(__uint_as_float(w.y & 0xffff0000u), kv.w, a3);
  }
  return (a0 + a1) + (a2 + a3);
}

// ==================== sequential scan ====================
// 1 block/batch-row, 1024 threads: j = t&255 (column), kq = t>>8 (wave-group k-slice).
// RK4 phase 1 (A·h, precision-critical) streams fp32 W4h from L2; phases 2-4 (corrections
// scaled by dt) read a bf16 copy of W4h RESIDENT IN LDS (128 KB) — deterministic on-chip
// residency, no register-allocator cooperation needed (r5/r6 lesson). GRU matvec/gates/LN/h
// stay double with fp32 weights streamed. All LDS h/k reads are wave-broadcast.
// Dynamic LDS: 143,616 B.
__global__ __launch_bounds__(1024, 4)
void scan_kernel(const float* __restrict__ gi, const float* __restrict__ u,
                 const float* __restrict__ ts,
                 const float* __restrict__ W4h, const float* __restrict__ W4hh,
                 const float* __restrict__ bhh,
                 const float* __restrict__ nog, const float* __restrict__ nob,
                 const float* __restrict__ ngg, const float* __restrict__ ngb,
                 float* __restrict__ hseq)
{
  extern __shared__ __align__(16) char smem[];
  uint2*  wb   = (uint2*)smem;                  // [64][256] bf16x4  = 131072 B
  double* hs   = (double*)(smem + 131072);      // h (double)          2048 B
  float*  hsf  = (float*)(smem + 133120);       // h (fp32)            1024 B
  float*  kb   = (float*)(smem + 134144);       // RK4 k staging       1024 B
  double* sc_d = (double*)(smem + 135168);      // GRU partials        8192 B
  float*  sc_f = (float*)(smem + 135168);       // RK4 partials (alias, 4096 B)
  double* red  = (double*)(smem + 143360);      // LN reduce            256 B

  const int b = blockIdx.x;
  const int t = threadIdx.x;
  const int j = t & 255;         // output column
  const int kq = t >> 8;         // k-slice group 0..3 (whole waves)
  const int kbase = kq << 6;
  const uint2* wbrow = wb + (kq << 12);

  // build bf16 W4h in LDS (one-time, coalesced)
  for (int e = t; e < 16384; e += 1024) {
    int row = e >> 8, j2 = e & 255;
    float4 w4 = *(const float4*)(W4h + (row << 10) + (j2 << 2));
    wb[e] = make_uint2((unsigned)f2bf(w4.x) | ((unsigned)f2bf(w4.y) << 16),
                       (unsigned)f2bf(w4.z) | ((unsigned)f2bf(w4.w) << 16));
  }

  const double gng = (double)ngg[j], gnb = (double)ngb[j];
  const double gog = (double)nog[j], gob = (double)nob[j];
  const double bhr = (double)bhh[j], bhz = (double)bhh[256 + j], bhn = (double)bhh[512 + j];

  double h = 0.0;
  // h0 = LN_gru(gru(x0, 0));  gh = bhh since h=0
  {
    const i64 row0 = (i64)b * 512;
    double h0 = 0.0;
    if (kq == 0) {
      double ir = (double)gi[row0 * 768 + j];
      double iz = (double)gi[row0 * 768 + 256 + j];
      double inn = (double)gi[row0 * 768 + 512 + j];
      double rr = 1.0 / (1.0 + exp(-(ir + bhr)));
      double zz = 1.0 / (1.0 + exp(-(iz + bhz)));
      double nn = tanh(inn + rr * bhn);
      h0 = (1.0 - zz) * nn;
    }
    double2 s0 = blockSum2d_1024(h0, h0 * h0, red);  // barriers also cover wb init
    double mean = s0.x * (1.0 / 256.0);
    double var = s0.y * (1.0 / 256.0) - mean * mean;
    var = var > 0.0 ? var : 0.0;
    if (kq == 0) {
      h0 = (h0 - mean) / sqrt(var + 1e-5) * gng + gnb;
      hs[j] = h0; hsf[j] = (float)h0;
      hseq[row0 * 256 + j] = (float)h0;
      h = h0;
    }
    __syncthreads();
  }

  for (int s = 0; s < 511; ++s) {
    const double dt = (double)ts[b * 512 + s + 1] - (double)ts[b * 512 + s];  // exact
    const float dtf = (float)dt;
    const i64 row = (i64)(b * 512 + s + 1);

    // prefetch (kq==0 rows only)
    float u_j = 0.f, ir2f = 0.f, iz2f = 0.f, in2f = 0.f;
    if (kq == 0) {
      u_j = u[row * 256 + j];
      ir2f = gi[row * 768 + j];
      iz2f = gi[row * 768 + 256 + j];
      in2f = gi[row * 768 + 512 + j];
    }

    // ---- RK4 phase 1: a = A·h + u (fp32 weights streamed from L2, unscaled path) ----
    float a_s = 0.f, k1s = 0.f, k2s = 0.f, k3s = 0.f, k4s = 0.f;
    {
      float a0 = 0.f, a1 = 0.f, a2 = 0.f, a3 = 0.f;
#pragma unroll
      for (int m4 = 0; m4 < 16; ++m4) {
        float4 w = *(const float4*)(W4h + (((kq << 4) + m4) << 10) + (j << 2));
        float4 hv = *(const float4*)(hsf + kbase + (m4 << 2));
        a0 = fmaf(w.x, hv.x, a0); a1 = fmaf(w.y, hv.y, a1);
        a2 = fmaf(w.z, hv.z, a2); a3 = fmaf(w.w, hv.w, a3);
      }
      sc_f[t] = (a0 + a1) + (a2 + a3);
    }
    __syncthreads();
    if (kq == 0) {
      a_s = sc_f[j] + sc_f[j + 256] + sc_f[j + 512] + sc_f[j + 768] + u_j;
      k1s = tanhf(a_s);
      kb[j] = k1s;
    }
    __syncthreads();
    // ---- RK4 phases 2-4: corrections (bf16 LDS weights; enter tanh scaled by dt) ----
    sc_f[t] = dot64bf(wbrow, j, kb + kbase);
    __syncthreads();
    if (kq == 0) {
      float bsum = sc_f[j] + sc_f[j + 256] + sc_f[j + 512] + sc_f[j + 768];
      k2s = tanhf(fmaf(0.5f * dtf, bsum, a_s));
      kb[j] = k2s;
    }
    __syncthreads();
    sc_f[t] = dot64bf(wbrow, j, kb + kbase);
    __syncthreads();
    if (kq == 0) {
      float bsum = sc_f[j] + sc_f[j + 256] + sc_f[j + 512] + sc_f[j + 768];
      k3s = tanhf(fmaf(0.5f * dtf, bsum, a_s));
      kb[j] = k3s;
    }
    __syncthreads();
    sc_f[t] = dot64bf(wbrow, j, kb + kbase);
    __syncthreads();
    if (kq == 0) {
      float bsum = sc_f[j] + sc_f[j + 256] + sc_f[j + 512] + sc_f[j + 768];
      k4s = tanhf(fmaf(dtf, bsum, a_s));
    }

    double hode = 0.0;
    if (kq == 0) {
      hode = h + dt * (1.0 / 6.0) *
             ((double)k1s + 2.0 * (double)k2s + 2.0 * (double)k3s + (double)k4s);
    }
    // LN_ode (double; kq!=0 contribute 0)
    {
      double2 so = blockSum2d_1024(hode, hode * hode, red);
      double mean = so.x * (1.0 / 256.0);
      double var = so.y * (1.0 / 256.0) - mean * mean;
      var = var > 0.0 ? var : 0.0;
      if (kq == 0) {
        hode = (hode - mean) / sqrt(var + 1e-5) * gog + gob;
        hs[j] = hode;
      }
    }
    __syncthreads();

    // ---- GRU hidden matvec (double acc, fp32 weights streamed from L2) ----
    double g0 = 0.0, g1 = 0.0, g2 = 0.0;
    {
#pragma unroll 2
      for (int m4 = 0; m4 < 16; ++m4) {
        const double2* hp = (const double2*)(hs + kbase + (m4 << 2));  // wave-broadcast
        double2 ha = hp[0], hb = hp[1];
        const float* base = W4hh + ((kq << 4) + m4) * 3072 + (j << 2);
        float4 w0 = *(const float4*)(base);
        float4 w1 = *(const float4*)(base + 1024);
        float4 w2 = *(const float4*)(base + 2048);
        g0 += (double)w0.x * ha.x + (double)w0.y * ha.y + (double)w0.z * hb.x + (double)w0.w * hb.y;
        g1 += (double)w1.x * ha.x + (double)w1.y * ha.y + (double)w1.z * hb.x + (double)w1.w * hb.y;
        g2 += (double)w2.x * ha.x + (double)w2.y * ha.y + (double)w2.z * hb.x + (double)w2.w * hb.y;
      }
    }
    // 3-round reduction through the 8 KB scratch (sc_d)
    double G0 = 0.0, G1 = 0.0, G2 = 0.0;
    sc_d[t] = g0; __syncthreads();
    if (kq == 0) G0 = sc_d[j] + sc_d[j + 256] + sc_d[j + 512] + sc_d[j + 768];
    __syncthreads();
    sc_d[t] = g1; __syncthreads();
    if (kq == 0) G1 = sc_d[j] + sc_d[j + 256] + sc_d[j + 512] + sc_d[j + 768];
    __syncthreads();
    sc_d[t] = g2; __syncthreads();
    double hg = 0.0;
    if (kq == 0) {
      G2 = sc_d[j] + sc_d[j + 256] + sc_d[j + 512] + sc_d[j + 768];
      double hodev = hs[j];
      double rr = 1.0 / (1.0 + exp(-((double)ir2f + G0 + bhr)));
      double zz = 1.0 / (1.0 + exp(-((double)iz2f + G1 + bhz)));
      double nn = tanh((double)in2f + rr * (G2 + bhn));
      hg = (1.0 - zz) * nn + zz * hodev;
    }
    // LN_gru (double)
    {
      double2 sg = blockSum2d_1024(hg, hg * hg, red);
      double mean = sg.x * (1.0 / 256.0);
      double var = sg.y * (1.0 / 256.0) - mean * mean;
      var = var > 0.0 ? var : 0.0;
      if (kq == 0) {
        hg = (hg - mean) / sqrt(var + 1e-5) * gng + gnb;
        hs[j] = hg; hsf[j] = (float)hg;
        hseq[row * 256 + j] = (float)hg;
        h = hg;
      }
    }
    __syncthreads();
  }
}

// ==================== FiLM + TimeHybridEncoding: H = h + (1+gamma)*tme + beta ====================
__global__ __launch_bounds__(256)
void tme_kernel(const float* __restrict__ hseq, const float* __restrict__ gb,
                const float* __restrict__ ts,
                const float* __restrict__ te_a, const float* __restrict__ te_b,
                float* __restrict__ H)
{
  i64 idx = (i64)blockIdx.x * 256 + threadIdx.x;  // over 32*512*256
  int c = (int)(idx & 255);
  i64 bt = idx >> 8;
  double tv = (double)ts[bt];
  double tme;
  if (c & 1) {
    int i = c >> 1;
    tme = tv * (double)te_a[i] + (double)te_b[i];
  } else {
    int f = c >> 2;
    double freq = exp(-(log(2500.0) / 63.0) * (double)f) * 1.5707963267948966;
    double ph = tv * freq;
    tme = ((c >> 1) & 1) ? cos(ph) : sin(ph);
  }
  float gamma = gb[bt * 512 + c];
  float beta = gb[bt * 512 + 256 + c];
  H[idx] = hseq[idx] + (1.0f + gamma) * (float)tme + beta;
}

// ==================== LayerNorm over C=256 (one row per block) ====================
__global__ __launch_bounds__(256)
void ln256_f32(const float* __restrict__ in, const float* __restrict__ g,
               const float* __restrict__ b, float* __restrict__ out)
{
  __shared__ float red[8];
  i64 row = blockIdx.x;
  float v = in[row * 256 + threadIdx.x];
  out[row * 256 + threadIdx.x] = lnVal(v, g[threadIdx.x], b[threadIdx.x], red);
}

// ==================== fused flash-style attention (fp32) ====================
__global__ __launch_bounds__(256)
void attn_kernel(const float* __restrict__ qkv, float* __restrict__ O)
{
  __shared__ float Qs[32][68];
  __shared__ float Ks[64][68];
  __shared__ float Vs[64][68];
  int bid = blockIdx.x;
  int qb = bid & 15, bh = bid >> 4;
  int h = bh & 3, b = bh >> 2;
  int tid = threadIdx.x;
  int r = tid >> 3, dg = tid & 7;
  int lane = tid & 63;
  int q0 = qb * 32;
  i64 base = (i64)b * 512 * 768;
  {
    int rr = tid >> 3, c8 = (tid & 7) * 8;
    const float* src = qkv + base + (i64)(q0 + rr) * 768 + h * 64 + c8;
    *(float4*)&Qs[rr][c8] = *(const float4*)src;
    *(float4*)&Qs[rr][c8 + 4] = *(const float4*)(src + 4);
  }
  float m = -1e30f, l = 0.0f;
  float o[8] = {0.f, 0.f, 0.f, 0.f, 0.f, 0.f, 0.f, 0.f};
  for (int kt = 0; kt < 8; ++kt) {
    __syncthreads();
    {
      int kr = tid >> 2, c16 = (tid & 3) * 16;
      const float* srcK = qkv + base + (i64)(kt * 64 + kr) * 768 + 256 + h * 64 + c16;
      const float* srcV = srcK + 256;
#pragma unroll
      for (int ii = 0; ii < 4; ++ii) {
        *(float4*)&Ks[kr][c16 + ii * 4] = *(const float4*)(srcK + ii * 4);
        *(float4*)&Vs[kr][c16 + ii * 4] = *(const float4*)(srcV + ii * 4);
      }
    }
    __syncthreads();
    float s[8] = {0.f, 0.f, 0.f, 0.f, 0.f, 0.f, 0.f, 0.f};
#pragma unroll
    for (int d4 = 0; d4 < 16; ++d4) {
      float4 qv = *(const float4*)&Qs[r][d4 * 4];
#pragma unroll
      for (int i = 0; i < 8; ++i) {
        float4 kv = *(const float4*)&Ks[dg * 8 + i][d4 * 4];
        s[i] += qv.x * kv.x + qv.y * kv.y + qv.z * kv.z + qv.w * kv.w;
      }
    }
    float ms = -1e30f;
#pragma unroll
    for (int i = 0; i < 8; ++i) { s[i] *= 0.125f; ms = fmaxf(ms, s[i]); }
    ms = fmaxf(ms, __shfl_xor(ms, 1, 64));
    ms = fmaxf(ms, __shfl_xor(ms, 2, 64));
    ms = fmaxf(ms, __shfl_xor(ms, 4, 64));
    float mnew = fmaxf(m, ms);
    float p[8];
    float ls = 0.0f;
#pragma unroll
    for (int i = 0; i < 8; ++i) { p[i] = __expf(s[i] - mnew); ls += p[i]; }
    ls += __shfl_xor(ls, 1, 64);
    ls += __shfl_xor(ls, 2, 64);
    ls += __shfl_xor(ls, 4, 64);
    float alpha = __expf(m - mnew);
    l = l * alpha + ls;
#pragma unroll
    for (int i = 0; i < 8; ++i) o[i] *= alpha;
    m = mnew;
#pragma unroll
    for (int i = 0; i < 8; ++i) {
#pragma unroll
      for (int dgk = 0; dgk < 8; ++dgk) {
        float pv = __shfl(p[i], (lane & 56) | dgk, 64);
        int kk = dgk * 8 + i;
        float4 v0 = *(const float4*)&Vs[kk][dg * 8];
        float4 v1 = *(const float4*)&Vs[kk][dg * 8 + 4];
        o[0] += pv * v0.x; o[1] += pv * v0.y; o[2] += pv * v0.z; o[3] += pv * v0.w;
        o[4] += pv * v1.x; o[5] += pv * v1.y; o[6] += pv * v1.z; o[7] += pv * v1.w;
      }
    }
  }
  float invl = 1.0f / l;
  float* dst = O + (i64)(b * 512 + q0 + r) * 256 + h * 64 + dg * 8;
  float4 r0 = make_float4(o[0] * invl, o[1] * invl, o[2] * invl, o[3] * invl);
  float4 r1 = make_float4(o[4] * invl, o[5] * invl, o[6] * invl, o[7] * invl);
  *(float4*)dst = r0;
  *(float4*)(dst + 4) = r1;
}

// ==================== launcher ====================
extern "C" void kernel_launch(void* const* d_in, const int* in_sizes, int n_in,
                              void* d_out, int out_size, void* d_ws, size_t ws_size,
                              hipStream_t stream)
{
  (void)in_sizes; (void)n_in; (void)out_size;
  const float* x       = (const float*)d_in[0];
  const float* ts      = (const float*)d_in[1];
  const float* gru_Wih = (const float*)d_in[2];
  const float* gru_Whh = (const float*)d_in[3];
  const float* gru_bih = (const float*)d_in[4];
  const float* gru_bhh = (const float*)d_in[5];
  const float* ode_W   = (const float*)d_in[6];
  const float* ode_b   = (const float*)d_in[7];
  const float* nog     = (const float*)d_in[8];
  const float* nob     = (const float*)d_in[9];
  const float* ngg     = (const float*)d_in[10];
  const float* ngb     = (const float*)d_in[11];
  const float* film_W  = (const float*)d_in[12];
  const float* film_b  = (const float*)d_in[13];
  const float* te_a    = (const float*)d_in[14];
  const float* te_bb   = (const float*)d_in[15];
  const float* qkv_W   = (const float*)d_in[16];
  const float* qkv_b   = (const float*)d_in[17];
  const float* out_W   = (const float*)d_in[18];
  const float* out_b   = (const float*)d_in[19];
  const float* ln1_g   = (const float*)d_in[20];
  const float* ln1_b   = (const float*)d_in[21];
  const float* ln2_g   = (const float*)d_in[22];
  const float* ln2_b   = (const float*)d_in[23];
  const float* ff1_W   = (const float*)d_in[24];
  const float* ff1_b   = (const float*)d_in[25];
  const float* ff2_W   = (const float*)d_in[26];
  const float* ff2_b   = (const float*)d_in[27];
  const float* lnf_g   = (const float*)d_in[28];
  const float* lnf_b   = (const float*)d_in[29];

  // compact workspace layout (floats), lifetime-overlaid; total 25,427,968 fl = 101.7 MB
  const size_t NEED = 25427968ull * 4ull;
  if (ws_size < NEED) {  // sentinel: absmax ~1000 in bench => ws too small
    fill_kernel<<<16384, 256, 0, stream>>>((float*)d_out, 1000.0f);
    return;
  }
  float* ws   = (float*)d_ws;
  float* W4h  = ws;                 //     65,536
  float* W4hh = ws + 65536;         //    196,608
  float* SA   = ws + 262144;        //  4,194,304 : u -> sh -> aln -> f2
  float* SB   = ws + 4456448;       //  4,194,304 : dxb -> hseq -> Obuf -> ff1o(chunk)
  float* Hb   = ws + 8650752;       //  4,194,304 : H
  float* BIG  = ws + 12845056;      // 12,582,912 : gi -> gb -> qkv

  float* u = SA;  float* sh = SA;   float* aln = SA;  float* f2 = SA;
  float* dxb = SB; float* hseq = SB; float* Obuf = SB; float* ff1o = SB;
  float* gi = BIG; float* gb = BIG;  float* qkvb = BIG;

  const int MROW = 32 * 512;        // 16384
  const int SCAN_LDS = 143616;

  // allow >64KB dynamic LDS for the scan (gfx950 has 160KB/CU); ignore errors
  static int lds_attr_set = 0;
  if (!lds_attr_set) {
    (void)hipFuncSetAttribute((const void*)scan_kernel,
                              hipFuncAttributeMaxDynamicSharedMemorySize, SCAN_LDS);
    lds_attr_set = 1;
  }

  // 1. pack scan weights
  pack_weights<<<1024, 256, 0, stream>>>(ode_W, gru_Whh, W4h, W4hh);
  // 2. dx (double math)
  dx_kernel<<<MROW, 256, 0, stream>>>(x, ts, dxb);
  // 3. gi = x @ Wih^T + bih   [16384 x 768]  (double accumulate: feeds the scan)
  gemm_nt_t<double><<<dim3(12, 256), 256, 0, stream>>>(x, 256, gru_Wih, 256, gru_bih,
                                                       nullptr, gi, 768, MROW, 768, 256, 0);
  // 4-6. u[t>=1] = xi@Wxi^T + xp@Wxp^T + dx@Wdx^T + ode_b  (rows shifted by 1; double acc)
  gemm_nt_t<double><<<dim3(4, 256), 256, 0, stream>>>(x + 256, 256, ode_W + 256, 1024, ode_b,
                                                      nullptr, u + 256, 256, MROW - 1, 256, 256, 0);
  gemm_nt_t<double><<<dim3(4, 256), 256, 0, stream>>>(x, 256, ode_W + 512, 1024, nullptr,
                                                      u + 256, u + 256, 256, MROW - 1, 256, 256, 0);
  gemm_nt_t<double><<<dim3(4, 256), 256, 0, stream>>>(dxb + 256, 256, ode_W + 768, 1024, nullptr,
                                                      u + 256, u + 256, 256, MROW - 1, 256, 256, 0);
  // 7. sequential scan -> hseq (bf16 RK4 weights resident in 128KB LDS; dxb dead)
  scan_kernel<<<32, 1024, SCAN_LDS, stream>>>(gi, u, ts, W4h, W4hh, gru_bhh,
                                              nog, nob, ngg, ngb, hseq);
  // 8. sh = silu(hseq)   (u dead)
  silu_kernel<<<MROW, 256, 0, stream>>>(hseq, sh);
  // 9. gb = sh @ film_W^T + film_b   [16384 x 512]  (gi dead)
  gemm_nt_t<float><<<dim3(8, 256), 256, 0, stream>>>(sh, 256, film_W, 256, film_b, nullptr,
                                                     gb, 512, MROW, 512, 256, 0);
  // 10. H = hseq + (1+gamma)*tme + beta
  tme_kernel<<<MROW, 256, 0, stream>>>(hseq, gb, ts, te_a, te_bb, Hb);

  for (int l = 0; l < 2; ++l) {
    // 11. a = LN1(H)  (sh dead)
    ln256_f32<<<MROW, 256, 0, stream>>>(Hb, ln1_g + 256 * l, ln1_b + 256 * l, aln);
    // 12. qkv = a @ qkv_W^T + qkv_b  (gb dead)
    gemm_nt_t<float><<<dim3(12, 256), 256, 0, stream>>>(aln, 256, qkv_W + (i64)196608 * l, 256,
                                                        qkv_b + 768 * l, nullptr,
                                                        qkvb, 768, MROW, 768, 256, 0);
    // 13. attention  (hseq dead)
    attn_kernel<<<2048, 256, 0, stream>>>(qkvb, Obuf);
    // 14. H = H + O @ out_W^T + out_b
    gemm_nt_t<float><<<dim3(4, 256), 256, 0, stream>>>(Obuf, 256, out_W + (i64)65536 * l, 256,
                                                       out_b + 256 * l, Hb, Hb, 256,
                                                       MROW, 256, 256, 0);
    // 15. f2 = LN2(H)
    ln256_f32<<<MROW, 256, 0, stream>>>(Hb, ln2_g + 256 * l, ln2_b + 256 * l, f2);
    // 16/17. FFN in 4 row-chunks of 4096 (ff1o chunk fits SLOT_B; qkv dead)
    for (int c = 0; c < 4; ++c) {
      const int r0 = c * 4096;
      gemm_nt_t<float><<<dim3(16, 64), 256, 0, stream>>>(f2 + (i64)r0 * 256, 256,
                                                         ff1_W + (i64)262144 * l, 256,
                                                         ff1_b + 1024 * l, nullptr,
                                                         ff1o, 1024, 4096, 1024, 256, 1);
      gemm_nt_t<float><<<dim3(4, 64), 256, 0, stream>>>(ff1o, 1024,
                                                        ff2_W + (i64)262144 * l, 1024,
                                                        ff2_b + 256 * l,
                                                        Hb + (i64)r0 * 256, Hb + (i64)r0 * 256, 256,
                                                        4096, 256, 1024, 0);
    }
  }
  // 18. final LN -> fp32 output
  ln256_f32<<<MROW, 256, 0, stream>>>(Hb, lnf_g, lnf_b, (float*)d_out);
}

// Round 8
// 9425.872 us; speedup vs baseline: 1.3350x; 1.3350x over previous
//
#include <hip/hip_runtime.h>
#include <hip/hip_bf16.h>
#include <math.h>

typedef long long i64;

// ==================== block reduce helpers (256 threads, fp32) ====================
__device__ __forceinline__ float2 blockSum2_256(float a, float b, float* red) {
#pragma unroll
  for (int off = 32; off; off >>= 1) {
    a += __shfl_xor(a, off, 64);
    b += __shfl_xor(b, off, 64);
  }
  __syncthreads();
  if ((threadIdx.x & 63) == 0) {
    int w = threadIdx.x >> 6;
    red[w * 2 + 0] = a;
    red[w * 2 + 1] = b;
  }
  __syncthreads();
  return make_float2(red[0] + red[2] + red[4] + red[6],
                     red[1] + red[3] + red[5] + red[7]);
}

__device__ __forceinline__ float lnVal(float v, float g, float b, float* red) {
  float2 s = blockSum2_256(v, v * v, red);
  float mean = s.x * (1.0f / 256.0f);
  float var = s.y * (1.0f / 256.0f) - mean * mean;
  var = fmaxf(var, 0.0f);
  return (v - mean) * rsqrtf(var + 1e-5f) * g + b;
}

// wave-wide (64-lane) double pair reduce via shfl
__device__ __forceinline__ void waveRed2d(double& a, double& b) {
#pragma unroll
  for (int off = 32; off; off >>= 1) {
    a += __shfl_xor(a, off, 64);
    b += __shfl_xor(b, off, 64);
  }
}

// ==================== generic GEMM: C = act(A@W^T + bias) + add ====================
template <typename ACCT>
__global__ __launch_bounds__(256)
void gemm_nt_t(const float* __restrict__ A, int lda,
               const float* __restrict__ W, int ldw,
               const float* __restrict__ bias,
               const float* add,
               float* C, int ldc,
               int M, int N, int K, int relu)
{
  __shared__ float As[16][68];
  __shared__ float Ws[16][68];
  const int tid = threadIdx.x;
  const int tx = tid & 15, ty = tid >> 4;
  const int m0 = blockIdx.y * 64, n0 = blockIdx.x * 64;
  const int lrow = tid >> 2, lk = (tid & 3) << 2;
  ACCT acc[4][4] = {};
  for (int k0 = 0; k0 < K; k0 += 16) {
    float4 av = make_float4(0.f, 0.f, 0.f, 0.f);
    if (m0 + lrow < M) av = *(const float4*)(A + (i64)(m0 + lrow) * lda + k0 + lk);
    float4 wv = *(const float4*)(W + (i64)(n0 + lrow) * ldw + k0 + lk);
    As[lk + 0][lrow] = av.x; As[lk + 1][lrow] = av.y;
    As[lk + 2][lrow] = av.z; As[lk + 3][lrow] = av.w;
    Ws[lk + 0][lrow] = wv.x; Ws[lk + 1][lrow] = wv.y;
    Ws[lk + 2][lrow] = wv.z; Ws[lk + 3][lrow] = wv.w;
    __syncthreads();
#pragma unroll
    for (int kk = 0; kk < 16; ++kk) {
      ACCT a0 = (ACCT)As[kk][ty * 4 + 0], a1 = (ACCT)As[kk][ty * 4 + 1];
      ACCT a2 = (ACCT)As[kk][ty * 4 + 2], a3 = (ACCT)As[kk][ty * 4 + 3];
      ACCT b0 = (ACCT)Ws[kk][tx * 4 + 0], b1 = (ACCT)Ws[kk][tx * 4 + 1];
      ACCT b2 = (ACCT)Ws[kk][tx * 4 + 2], b3 = (ACCT)Ws[kk][tx * 4 + 3];
      acc[0][0] += a0 * b0; acc[0][1] += a0 * b1; acc[0][2] += a0 * b2; acc[0][3] += a0 * b3;
      acc[1][0] += a1 * b0; acc[1][1] += a1 * b1; acc[1][2] += a1 * b2; acc[1][3] += a1 * b3;
      acc[2][0] += a2 * b0; acc[2][1] += a2 * b1; acc[2][2] += a2 * b2; acc[2][3] += a2 * b3;
      acc[3][0] += a3 * b0; acc[3][1] += a3 * b1; acc[3][2] += a3 * b2; acc[3][3] += a3 * b3;
    }
    __syncthreads();
  }
#pragma unroll
  for (int i = 0; i < 4; ++i) {
    int m = m0 + ty * 4 + i;
    if (m >= M) continue;
#pragma unroll
    for (int j = 0; j < 4; ++j) {
      int n = n0 + tx * 4 + j;
      ACCT v = acc[i][j];
      if (bias) v += (ACCT)bias[n];
      if (relu) v = v > (ACCT)0 ? v : (ACCT)0;
      if (add) v += (ACCT)add[(i64)m * ldc + n];
      C[(i64)m * ldc + n] = (float)v;
    }
  }
}

// ==================== weight packing for the scan ====================
// W4h  [64][256][4]: W4h[(k>>2)*1024 + j*4 + (k&3)] = ode_W[j*1024 + k]   (k<256, j<256)
// W4hh [64][768][4]: W4hh[(k>>2)*3072 + j3*4 + (k&3)] = gru_Whh[j3*256 + k]
__global__ __launch_bounds__(256)
void pack_weights(const float* __restrict__ odeW, const float* __restrict__ Whh,
                  float* __restrict__ W4h, float* __restrict__ W4hh)
{
  int idx = blockIdx.x * 256 + threadIdx.x;
  if (idx < 65536) {
    int j = idx >> 8, k = idx & 255;
    W4h[((k >> 2) << 10) + (j << 2) + (k & 3)] = odeW[j * 1024 + k];
  } else {
    int t = idx - 65536;
    int j3 = t >> 8, k = t & 255;
    W4hh[(k >> 2) * 3072 + (j3 << 2) + (k & 3)] = Whh[j3 * 256 + k];
  }
}

// LN-fold row sums (double): SA1[j]=Σ_k A[j,k]·ngg[k], SA0[j]=Σ_k A[j,k]·ngb[k]
//                            SG1[j3]=Σ_k Whh[j3,k]·nog[k], SG0[j3]=Σ_k Whh[j3,k]·nob[k]
__global__ __launch_bounds__(256)
void pack_rowsums(const float* __restrict__ odeW, const float* __restrict__ Whh,
                  const float* __restrict__ ngg, const float* __restrict__ ngb,
                  const float* __restrict__ nog, const float* __restrict__ nob,
                  double* __restrict__ Sd)
{
  int r = blockIdx.x * 256 + threadIdx.x;  // 0..1023
  if (r < 256) {
    double s1 = 0.0, s0 = 0.0;
    for (int k = 0; k < 256; ++k) {
      double w = (double)odeW[r * 1024 + k];
      s1 += w * (double)ngg[k];
      s0 += w * (double)ngb[k];
    }
    Sd[r] = s1; Sd[256 + r] = s0;
  } else {
    int j3 = r - 256;  // 0..767
    double s1 = 0.0, s0 = 0.0;
    for (int k = 0; k < 256; ++k) {
      double w = (double)Whh[j3 * 256 + k];
      s1 += w * (double)nog[k];
      s0 += w * (double)nob[k];
    }
    Sd[512 + j3] = s1; Sd[1280 + j3] = s0;
  }
}

// ==================== dx = (x_t - x_{t-1}) / dt  (double math, fp32 store) ====================
__global__ __launch_bounds__(256)
void dx_kernel(const float* __restrict__ x, const float* __restrict__ ts,
               float* __restrict__ dx)
{
  i64 row = blockIdx.x;  // b*512 + t
  int c = threadIdx.x;
  int t = (int)(row & 511);
  float v = 0.0f;
  if (t > 0) {
    double dt = (double)ts[row] - (double)ts[row - 1];
    v = (float)(((double)x[row * 256 + c] - (double)x[(row - 1) * 256 + c]) / dt);
  }
  dx[row * 256 + c] = v;
}

// ==================== silu elementwise ====================
__global__ __launch_bounds__(256)
void silu_kernel(const float* __restrict__ in, float* __restrict__ out)
{
  i64 i = (i64)blockIdx.x * 256 + threadIdx.x;
  float v = in[i];
  out[i] = v / (1.0f + __expf(-v));
}

// ==================== sentinel fill (ws too small diagnostic) ====================
__global__ __launch_bounds__(256)
void fill_kernel(float* __restrict__ out, float v)
{
  i64 i = (i64)blockIdx.x * 256 + threadIdx.x;
  out[i] = v;
}

// fp32 dot over this thread's 64-k slice; W streamed (L2-hot), v wave-broadcast from LDS
__device__ __forceinline__ float dot64s(const float* __restrict__ W, int kq, int j,
                                        const float* __restrict__ v)
{
  float a0 = 0.f, a1 = 0.f, a2 = 0.f, a3 = 0.f;
#pragma unroll
  for (int m4 = 0; m4 < 16; ++m4) {
    float4 w = *(const float4*)(W + (((kq << 4) + m4) << 10) + (j << 2));
    float4 x = *(const float4*)(v + (m4 << 2));
    a0 = fmaf(w.x, x.x, a0); a1 = fmaf(w.y, x.y, a1);
    a2 = fmaf(w.z, x.z, a2); a3 = fmaf(w.w, x.w, a3);
  }
  return (a0 + a1) + (a2 + a3);
}

// ==================== sequential scan (LN-folded, 10 barriers/step) ====================
// 1 block/batch-row, 1024 threads: j = t&255 (column), kq = t>>8 (wave-group k-slice).
// LayerNorms are folded into the matvecs: W·LN(v) = inv·(W·(g⊙v)) − m·inv·S1 + S0 with
// S1,S0 precomputed in double (Sd). Matvecs run on RAW pre-LN vectors; mean/var come from
// wave-shfl reduces overlapped into the finish phases (no blockSum barriers).
// RK4 internals fp32 (dt-scaled); GRU matvec/gates and the h trajectory in double.
__global__ __launch_bounds__(1024, 4)
void scan_kernel(const float* __restrict__ gi, const float* __restrict__ u,
                 const float* __restrict__ ts,
                 const float* __restrict__ W4h, const float* __restrict__ W4hh,
                 const double* __restrict__ Sd,
                 const float* __restrict__ bhh,
                 const float* __restrict__ nog, const float* __restrict__ nob,
                 const float* __restrict__ ngg, const float* __restrict__ ngb,
                 float* __restrict__ hseq)
{
  const int b = blockIdx.x;
  const int t = threadIdx.x;
  const int j = t & 255;         // output column
  const int kq = t >> 8;         // k-slice group 0..3 (whole waves)
  const int kbase = kq << 6;
  const int lane = t & 63;
  const int wv = t >> 6;         // wave 0..15 (kq0 = waves 0..3)

  __shared__ __align__(16) float  hraw2f[256];     // gng ⊙ hg_raw (fp32, RK4 phase-1 input)
  __shared__ __align__(16) double vr2[256];        // gog ⊙ hode_raw (GRU matvec input)
  __shared__ __align__(16) float  kb[256];         // RK4 k staging
  __shared__ __align__(16) float  sc_f[1024];      // fp32 partials (RK4)
  __shared__ __align__(16) double predd[3][1024];  // double partials (GRU)
  __shared__ double redv[8];                       // hode mean/var wave sums
  __shared__ double redh[8];                       // hg mean/var wave sums

  const double gng = (double)ngg[j], gnb = (double)ngb[j];
  const double gog = (double)nog[j], gob = (double)nob[j];
  const double bhr = (double)bhh[j], bhz = (double)bhh[256 + j], bhn = (double)bhh[512 + j];
  // LN-fold constants (kq0 only uses them)
  const double sa1 = Sd[j], sa0 = Sd[256 + j];
  const double sg1r = Sd[512 + j],  sg0r = Sd[1280 + j];
  const double sg1z = Sd[768 + j],  sg0z = Sd[1536 + j];
  const double sg1n = Sd[1024 + j], sg0n = Sd[1792 + j];

  double hLN = 0.0, hg_raw = 0.0, mg = 0.0, invg = 1.0;

  // ---- init: h0 = LN_gru(gru(x0, 0)) ----
  {
    const i64 row0 = (i64)b * 512;
    if (kq == 0) {
      double ir = (double)gi[row0 * 768 + j];
      double iz = (double)gi[row0 * 768 + 256 + j];
      double inn = (double)gi[row0 * 768 + 512 + j];
      double rr = 1.0 / (1.0 + exp(-(ir + bhr)));
      double zz = 1.0 / (1.0 + exp(-(iz + bhz)));
      double nn = tanh(inn + rr * bhn);
      hg_raw = (1.0 - zz) * nn;
      hraw2f[j] = (float)(gng * hg_raw);
      double sa = hg_raw, sb = hg_raw * hg_raw;
      waveRed2d(sa, sb);
      if (lane == 0) { redh[wv * 2] = sa; redh[wv * 2 + 1] = sb; }
    }
    __syncthreads();
    if (kq == 0) {
      double S = redh[0] + redh[2] + redh[4] + redh[6];
      double Q = redh[1] + redh[3] + redh[5] + redh[7];
      mg = S * (1.0 / 256.0);
      double var = Q * (1.0 / 256.0) - mg * mg;
      var = var > 0.0 ? var : 0.0;
      invg = 1.0 / sqrt(var + 1e-5);
      hLN = (hg_raw - mg) * invg * gng + gnb;
      hseq[row0 * 256 + j] = (float)hLN;
    }
  }
  __syncthreads();

  for (int s = 0; s < 511; ++s) {
    const double dt = (double)ts[b * 512 + s + 1] - (double)ts[b * 512 + s];  // exact
    const float dtf = (float)dt;
    const i64 row = (i64)(b * 512 + s + 1);

    // prefetch (kq0 rows only)
    float u_j = 0.f, ir2f = 0.f, iz2f = 0.f, in2f = 0.f;
    if (kq == 0) {
      u_j = u[row * 256 + j];
      ir2f = gi[row * 768 + j];
      iz2f = gi[row * 768 + 256 + j];
      in2f = gi[row * 768 + 512 + j];
    }

    // P1: a-dot on raw h (LN folded)
    sc_f[t] = dot64s(W4h, kq, j, hraw2f + kbase);
    __syncthreads();                                                    // #1
    float a_s = 0.f, k1s = 0.f, k2s = 0.f, k3s = 0.f, k4s = 0.f;
    if (kq == 0) {
      double psum = (double)(sc_f[j] + sc_f[j + 256] + sc_f[j + 512] + sc_f[j + 768]);
      double a_d = psum * invg - mg * invg * sa1 + sa0 + (double)u_j;
      a_s = (float)a_d;
      k1s = tanhf(a_s);
      kb[j] = k1s;
    }
    __syncthreads();                                                    // #2
    // P2..P4: RK4 correction dots (plain weights; dt-scaled path)
    sc_f[t] = dot64s(W4h, kq, j, kb + kbase);
    __syncthreads();                                                    // #3
    if (kq == 0) {
      float bs = sc_f[j] + sc_f[j + 256] + sc_f[j + 512] + sc_f[j + 768];
      k2s = tanhf(fmaf(0.5f * dtf, bs, a_s));
      kb[j] = k2s;
    }
    __syncthreads();                                                    // #4
    sc_f[t] = dot64s(W4h, kq, j, kb + kbase);
    __syncthreads();                                                    // #5
    if (kq == 0) {
      float bs = sc_f[j] + sc_f[j + 256] + sc_f[j + 512] + sc_f[j + 768];
      k3s = tanhf(fmaf(0.5f * dtf, bs, a_s));
      kb[j] = k3s;
    }
    __syncthreads();                                                    // #6
    sc_f[t] = dot64s(W4h, kq, j, kb + kbase);
    __syncthreads();                                                    // #7
    double hode_raw = 0.0;
    if (kq == 0) {
      float bs = sc_f[j] + sc_f[j + 256] + sc_f[j + 512] + sc_f[j + 768];
      k4s = tanhf(fmaf(dtf, bs, a_s));
      hode_raw = hLN + dt * (1.0 / 6.0) *
                 ((double)k1s + 2.0 * (double)k2s + 2.0 * (double)k3s + (double)k4s);
      vr2[j] = gog * hode_raw;
      double sa = hode_raw, sb = hode_raw * hode_raw;
      waveRed2d(sa, sb);
      if (lane == 0) { redv[wv * 2] = sa; redv[wv * 2 + 1] = sb; }
    }
    __syncthreads();                                                    // #8
    // P5: GRU matvec on raw hode (LN folded), double accumulate
    {
      double g0 = 0.0, g1 = 0.0, g2 = 0.0;
#pragma unroll 2
      for (int m4 = 0; m4 < 16; ++m4) {
        const double2* hp = (const double2*)(vr2 + kbase + (m4 << 2));  // wave-broadcast
        double2 ha = hp[0], hb2 = hp[1];
        const float* base = W4hh + ((kq << 4) + m4) * 3072 + (j << 2);
        float4 w0 = *(const float4*)(base);
        float4 w1 = *(const float4*)(base + 1024);
        float4 w2 = *(const float4*)(base + 2048);
        g0 += (double)w0.x * ha.x + (double)w0.y * ha.y + (double)w0.z * hb2.x + (double)w0.w * hb2.y;
        g1 += (double)w1.x * ha.x + (double)w1.y * ha.y + (double)w1.z * hb2.x + (double)w1.w * hb2.y;
        g2 += (double)w2.x * ha.x + (double)w2.y * ha.y + (double)w2.z * hb2.x + (double)w2.w * hb2.y;
      }
      predd[0][t] = g0; predd[1][t] = g1; predd[2][t] = g2;
    }
    __syncthreads();                                                    // #9
    if (kq == 0) {
      double mo = (redv[0] + redv[2] + redv[4] + redv[6]) * (1.0 / 256.0);
      double qo = (redv[1] + redv[3] + redv[5] + redv[7]) * (1.0 / 256.0);
      double var = qo - mo * mo; var = var > 0.0 ? var : 0.0;
      double invo = 1.0 / sqrt(var + 1e-5);
      double G0 = (predd[0][j] + predd[0][j + 256] + predd[0][j + 512] + predd[0][j + 768]) * invo
                  - mo * invo * sg1r + sg0r;
      double G1 = (predd[1][j] + predd[1][j + 256] + predd[1][j + 512] + predd[1][j + 768]) * invo
                  - mo * invo * sg1z + sg0z;
      double G2 = (predd[2][j] + predd[2][j + 256] + predd[2][j + 512] + predd[2][j + 768]) * invo
                  - mo * invo * sg1n + sg0n;
      double rr = 1.0 / (1.0 + exp(-((double)ir2f + G0 + bhr)));
      double zz = 1.0 / (1.0 + exp(-((double)iz2f + G1 + bhz)));
      double nn = tanh((double)in2f + rr * (G2 + bhn));
      double hodeLN = (hode_raw - mo) * invo * gog + gob;
      hg_raw = (1.0 - zz) * nn + zz * hodeLN;
      hraw2f[j] = (float)(gng * hg_raw);
      double sa = hg_raw, sb = hg_raw * hg_raw;
      waveRed2d(sa, sb);
      if (lane == 0) { redh[wv * 2] = sa; redh[wv * 2 + 1] = sb; }
    }
    __syncthreads();                                                    // #10
    if (kq == 0) {
      double S = redh[0] + redh[2] + redh[4] + redh[6];
      double Q = redh[1] + redh[3] + redh[5] + redh[7];
      mg = S * (1.0 / 256.0);
      double var = Q * (1.0 / 256.0) - mg * mg;
      var = var > 0.0 ? var : 0.0;
      invg = 1.0 / sqrt(var + 1e-5);
      hLN = (hg_raw - mg) * invg * gng + gnb;
      hseq[row * 256 + j] = (float)hLN;
    }
    // no trailing barrier: next P1 only reads hraw2f (fenced by #10); mg/invg/hLN
    // are kq0 registers consumed by the same threads.
  }
}

// ==================== FiLM + TimeHybridEncoding: H = h + (1+gamma)*tme + beta ====================
__global__ __launch_bounds__(256)
void tme_kernel(const float* __restrict__ hseq, const float* __restrict__ gb,
                const float* __restrict__ ts,
                const float* __restrict__ te_a, const float* __restrict__ te_b,
                float* __restrict__ H)
{
  i64 idx = (i64)blockIdx.x * 256 + threadIdx.x;  // over 32*512*256
  int c = (int)(idx & 255);
  i64 bt = idx >> 8;
  double tv = (double)ts[bt];
  double tme;
  if (c & 1) {
    int i = c >> 1;
    tme = tv * (double)te_a[i] + (double)te_b[i];
  } else {
    int f = c >> 2;
    double freq = exp(-(log(2500.0) / 63.0) * (double)f) * 1.5707963267948966;
    double ph = tv * freq;
    tme = ((c >> 1) & 1) ? cos(ph) : sin(ph);
  }
  float gamma = gb[bt * 512 + c];
  float beta = gb[bt * 512 + 256 + c];
  H[idx] = hseq[idx] + (1.0f + gamma) * (float)tme + beta;
}

// ==================== LayerNorm over C=256 (one row per block) ====================
__global__ __launch_bounds__(256)
void ln256_f32(const float* __restrict__ in, const float* __restrict__ g,
               const float* __restrict__ b, float* __restrict__ out)
{
  __shared__ float red[8];
  i64 row = blockIdx.x;
  float v = in[row * 256 + threadIdx.x];
  out[row * 256 + threadIdx.x] = lnVal(v, g[threadIdx.x], b[threadIdx.x], red);
}

// ==================== fused flash-style attention (fp32) ====================
__global__ __launch_bounds__(256)
void attn_kernel(const float* __restrict__ qkv, float* __restrict__ O)
{
  __shared__ float Qs[32][68];
  __shared__ float Ks[64][68];
  __shared__ float Vs[64][68];
  int bid = blockIdx.x;
  int qb = bid & 15, bh = bid >> 4;
  int h = bh & 3, b = bh >> 2;
  int tid = threadIdx.x;
  int r = tid >> 3, dg = tid & 7;
  int lane = tid & 63;
  int q0 = qb * 32;
  i64 base = (i64)b * 512 * 768;
  {
    int rr = tid >> 3, c8 = (tid & 7) * 8;
    const float* src = qkv + base + (i64)(q0 + rr) * 768 + h * 64 + c8;
    *(float4*)&Qs[rr][c8] = *(const float4*)src;
    *(float4*)&Qs[rr][c8 + 4] = *(const float4*)(src + 4);
  }
  float m = -1e30f, l = 0.0f;
  float o[8] = {0.f, 0.f, 0.f, 0.f, 0.f, 0.f, 0.f, 0.f};
  for (int kt = 0; kt < 8; ++kt) {
    __syncthreads();
    {
      int kr = tid >> 2, c16 = (tid & 3) * 16;
      const float* srcK = qkv + base + (i64)(kt * 64 + kr) * 768 + 256 + h * 64 + c16;
      const float* srcV = srcK + 256;
#pragma unroll
      for (int ii = 0; ii < 4; ++ii) {
        *(float4*)&Ks[kr][c16 + ii * 4] = *(const float4*)(srcK + ii * 4);
        *(float4*)&Vs[kr][c16 + ii * 4] = *(const float4*)(srcV + ii * 4);
      }
    }
    __syncthreads();
    float s[8] = {0.f, 0.f, 0.f, 0.f, 0.f, 0.f, 0.f, 0.f};
#pragma unroll
    for (int d4 = 0; d4 < 16; ++d4) {
      float4 qv = *(const float4*)&Qs[r][d4 * 4];
#pragma unroll
      for (int i = 0; i < 8; ++i) {
        float4 kv = *(const float4*)&Ks[dg * 8 + i][d4 * 4];
        s[i] += qv.x * kv.x + qv.y * kv.y + qv.z * kv.z + qv.w * kv.w;
      }
    }
    float ms = -1e30f;
#pragma unroll
    for (int i = 0; i < 8; ++i) { s[i] *= 0.125f; ms = fmaxf(ms, s[i]); }
    ms = fmaxf(ms, __shfl_xor(ms, 1, 64));
    ms = fmaxf(ms, __shfl_xor(ms, 2, 64));
    ms = fmaxf(ms, __shfl_xor(ms, 4, 64));
    float mnew = fmaxf(m, ms);
    float p[8];
    float ls = 0.0f;
#pragma unroll
    for (int i = 0; i < 8; ++i) { p[i] = __expf(s[i] - mnew); ls += p[i]; }
    ls += __shfl_xor(ls, 1, 64);
    ls += __shfl_xor(ls, 2, 64);
    ls += __shfl_xor(ls, 4, 64);
    float alpha = __expf(m - mnew);
    l = l * alpha + ls;
#pragma unroll
    for (int i = 0; i < 8; ++i) o[i] *= alpha;
    m = mnew;
#pragma unroll
    for (int i = 0; i < 8; ++i) {
#pragma unroll
      for (int dgk = 0; dgk < 8; ++dgk) {
        float pv = __shfl(p[i], (lane & 56) | dgk, 64);
        int kk = dgk * 8 + i;
        float4 v0 = *(const float4*)&Vs[kk][dg * 8];
        float4 v1 = *(const float4*)&Vs[kk][dg * 8 + 4];
        o[0] += pv * v0.x; o[1] += pv * v0.y; o[2] += pv * v0.z; o[3] += pv * v0.w;
        o[4] += pv * v1.x; o[5] += pv * v1.y; o[6] += pv * v1.z; o[7] += pv * v1.w;
      }
    }
  }
  float invl = 1.0f / l;
  float* dst = O + (i64)(b * 512 + q0 + r) * 256 + h * 64 + dg * 8;
  float4 r0 = make_float4(o[0] * invl, o[1] * invl, o[2] * invl, o[3] * invl);
  float4 r1 = make_float4(o[4] * invl, o[5] * invl, o[6] * invl, o[7] * invl);
  *(float4*)dst = r0;
  *(float4*)(dst + 4) = r1;
}

// ==================== launcher ====================
extern "C" void kernel_launch(void* const* d_in, const int* in_sizes, int n_in,
                              void* d_out, int out_size, void* d_ws, size_t ws_size,
                              hipStream_t stream)
{
  (void)in_sizes; (void)n_in; (void)out_size;
  const float* x       = (const float*)d_in[0];
  const float* ts      = (const float*)d_in[1];
  const float* gru_Wih = (const float*)d_in[2];
  const float* gru_Whh = (const float*)d_in[3];
  const float* gru_bih = (const float*)d_in[4];
  const float* gru_bhh = (const float*)d_in[5];
  const float* ode_W   = (const float*)d_in[6];
  const float* ode_b   = (const float*)d_in[7];
  const float* nog     = (const float*)d_in[8];
  const float* nob     = (const float*)d_in[9];
  const float* ngg     = (const float*)d_in[10];
  const float* ngb     = (const float*)d_in[11];
  const float* film_W  = (const float*)d_in[12];
  const float* film_b  = (const float*)d_in[13];
  const float* te_a    = (const float*)d_in[14];
  const float* te_bb   = (const float*)d_in[15];
  const float* qkv_W   = (const float*)d_in[16];
  const float* qkv_b   = (const float*)d_in[17];
  const float* out_W   = (const float*)d_in[18];
  const float* out_b   = (const float*)d_in[19];
  const float* ln1_g   = (const float*)d_in[20];
  const float* ln1_b   = (const float*)d_in[21];
  const float* ln2_g   = (const float*)d_in[22];
  const float* ln2_b   = (const float*)d_in[23];
  const float* ff1_W   = (const float*)d_in[24];
  const float* ff1_b   = (const float*)d_in[25];
  const float* ff2_W   = (const float*)d_in[26];
  const float* ff2_b   = (const float*)d_in[27];
  const float* lnf_g   = (const float*)d_in[28];
  const float* lnf_b   = (const float*)d_in[29];

  // workspace layout (floats), lifetime-overlaid; total 25,432,064 fl ≈ 101.7 MB
  const size_t NEED = 25432064ull * 4ull;
  if (ws_size < NEED) {  // sentinel: absmax ~1000 in bench => ws too small
    fill_kernel<<<16384, 256, 0, stream>>>((float*)d_out, 1000.0f);
    return;
  }
  float*  ws   = (float*)d_ws;
  float*  W4h  = ws;                 //     65,536
  float*  W4hh = ws + 65536;         //    196,608
  double* Sd   = (double*)(ws + 262144);  // 2,048 doubles (4,096 fl)
  float*  SA   = ws + 266240;        //  4,194,304 : u -> sh -> aln -> f2
  float*  SB   = ws + 4460544;       //  4,194,304 : dxb -> hseq -> Obuf -> ff1o(chunk)
  float*  Hb   = ws + 8654848;       //  4,194,304 : H
  float*  BIG  = ws + 12849152;      // 12,582,912 : gi -> gb -> qkv

  float* u = SA;  float* sh = SA;   float* aln = SA;  float* f2 = SA;
  float* dxb = SB; float* hseq = SB; float* Obuf = SB; float* ff1o = SB;
  float* gi = BIG; float* gb = BIG;  float* qkvb = BIG;

  const int MROW = 32 * 512;        // 16384

  // 1. pack scan weights + LN-fold row sums
  pack_weights<<<1024, 256, 0, stream>>>(ode_W, gru_Whh, W4h, W4hh);
  pack_rowsums<<<4, 256, 0, stream>>>(ode_W, gru_Whh, ngg, ngb, nog, nob, Sd);
  // 2. dx (double math)
  dx_kernel<<<MROW, 256, 0, stream>>>(x, ts, dxb);
  // 3. gi = x @ Wih^T + bih   [16384 x 768]  (double accumulate: feeds the scan)
  gemm_nt_t<double><<<dim3(12, 256), 256, 0, stream>>>(x, 256, gru_Wih, 256, gru_bih,
                                                       nullptr, gi, 768, MROW, 768, 256, 0);
  // 4-6. u[t>=1] = xi@Wxi^T + xp@Wxp^T + dx@Wdx^T + ode_b  (rows shifted by 1; double acc)
  gemm_nt_t<double><<<dim3(4, 256), 256, 0, stream>>>(x + 256, 256, ode_W + 256, 1024, ode_b,
                                                      nullptr, u + 256, 256, MROW - 1, 256, 256, 0);
  gemm_nt_t<double><<<dim3(4, 256), 256, 0, stream>>>(x, 256, ode_W + 512, 1024, nullptr,
                                                      u + 256, u + 256, 256, MROW - 1, 256, 256, 0);
  gemm_nt_t<double><<<dim3(4, 256), 256, 0, stream>>>(dxb + 256, 256, ode_W + 768, 1024, nullptr,
                                                      u + 256, u + 256, 256, MROW - 1, 256, 256, 0);
  // 7. sequential scan -> hseq (LN-folded, 10 barriers/step; dxb dead)
  scan_kernel<<<32, 1024, 0, stream>>>(gi, u, ts, W4h, W4hh, Sd, gru_bhh,
                                       nog, nob, ngg, ngb, hseq);
  // 8. sh = silu(hseq)   (u dead)
  silu_kernel<<<MROW, 256, 0, stream>>>(hseq, sh);
  // 9. gb = sh @ film_W^T + film_b   [16384 x 512]  (gi dead)
  gemm_nt_t<float><<<dim3(8, 256), 256, 0, stream>>>(sh, 256, film_W, 256, film_b, nullptr,
                                                     gb, 512, MROW, 512, 256, 0);
  // 10. H = hseq + (1+gamma)*tme + beta
  tme_kernel<<<MROW, 256, 0, stream>>>(hseq, gb, ts, te_a, te_bb, Hb);

  for (int l = 0; l < 2; ++l) {
    // 11. a = LN1(H)  (sh dead)
    ln256_f32<<<MROW, 256, 0, stream>>>(Hb, ln1_g + 256 * l, ln1_b + 256 * l, aln);
    // 12. qkv = a @ qkv_W^T + qkv_b  (gb dead)
    gemm_nt_t<float><<<dim3(12, 256), 256, 0, stream>>>(aln, 256, qkv_W + (i64)196608 * l, 256,
                                                        qkv_b + 768 * l, nullptr,
                                                        qkvb, 768, MROW, 768, 256, 0);
    // 13. attention  (hseq dead)
    attn_kernel<<<2048, 256, 0, stream>>>(qkvb, Obuf);
    // 14. H = H + O @ out_W^T + out_b
    gemm_nt_t<float><<<dim3(4, 256), 256, 0, stream>>>(Obuf, 256, out_W + (i64)65536 * l, 256,
                                                       out_b + 256 * l, Hb, Hb, 256,
                                                       MROW, 256, 256, 0);
    // 15. f2 = LN2(H)
    ln256_f32<<<MROW, 256, 0, stream>>>(Hb, ln2_g + 256 * l, ln2_b + 256 * l, f2);
    // 16/17. FFN in 4 row-chunks of 4096 (ff1o chunk fits SLOT_B; qkv dead)
    for (int c = 0; c < 4; ++c) {
      const int r0 = c * 4096;
      gemm_nt_t<float><<<dim3(16, 64), 256, 0, stream>>>(f2 + (i64)r0 * 256, 256,
                                                         ff1_W + (i64)262144 * l, 256,
                                                         ff1_b + 1024 * l, nullptr,
                                                         ff1o, 1024, 4096, 1024, 256, 1);
      gemm_nt_t<float><<<dim3(4, 64), 256, 0, stream>>>(ff1o, 1024,
                                                        ff2_W + (i64)262144 * l, 1024,
                                                        ff2_b + 256 * l,
                                                        Hb + (i64)r0 * 256, Hb + (i64)r0 * 256, 256,
                                                        4096, 256, 1024, 0);
    }
  }
  // 18. final LN -> fp32 output
  ln256_f32<<<MROW, 256, 0, stream>>>(Hb, lnf_g, lnf_b, (float*)d_out);
}